// Round 1
// baseline (3695.644 us; speedup 1.0000x reference)
//
#include <hip/hip_runtime.h>
#include <math.h>

#define B_ 4
#define N_ 32768
#define S_ 8192
#define K_ 16
#define CIN 64
#define COUT 128
#define MID_ 32
#define EPS_ 1e-5f

__device__ __forceinline__ float dot4(float4 a, float4 b) {
  return a.x*b.x + a.y*b.y + a.z*b.z + a.w*b.w;
}

// One block (128 threads) per sampled point: full attention block through Wpost
// (pre-GroupNorm). Thread tid owns output channel o = tid.
__global__ __launch_bounds__(128) void k_point(
    const float* __restrict__ xyz, const float* __restrict__ feats,
    const int* __restrict__ idx_fps, const int* __restrict__ idx_knn,
    const float* __restrict__ Wq, const float* __restrict__ Wk,
    const float* __restrict__ Wv, const float* __restrict__ Wp1,
    const float* __restrict__ Wp2, const float* __restrict__ Wa1,
    const float* __restrict__ Wa2, const float* __restrict__ Wproj,
    const float* __restrict__ ln_w, const float* __restrict__ ln_b,
    const float* __restrict__ Wres, const float* __restrict__ Wpost,
    float* __restrict__ out_xyz, float* __restrict__ out_main)
{
  const int bs = blockIdx.x;
  const int b = bs >> 13;          // S_=8192
  const int s = bs & (S_ - 1);
  const int tid = threadIdx.x;

  __shared__ float sfeat[CIN];
  __shared__ float nfeat[K_][CIN];
  __shared__ float rel[K_][4];
  __shared__ float t1[K_][COUT];     // relu(rel @ Wp1^T), 16x128
  __shared__ float hsh[K_][132];     // h, padded (+4) to break bank conflicts
  __shared__ float ash[K_][MID_];    // relu(h @ Wa1^T)
  __shared__ float vec[COUT];        // reused: attn-out, then LN-out
  __shared__ float red[4];
  __shared__ int kn[K_];

  const int sidx = idx_fps[b*S_ + s];
  if (tid < K_) kn[tid] = idx_knn[((size_t)(b*S_ + s))*K_ + tid];
  if (tid < CIN) sfeat[tid] = feats[((size_t)(b*N_ + sidx))*CIN + tid];
  if (tid < 3) out_xyz[((size_t)(b*S_ + s))*3 + tid] =
      xyz[((size_t)(b*N_ + sidx))*3 + tid];
  __syncthreads();

  for (int i = tid; i < K_*CIN; i += 128) {
    int k = i >> 6, c = i & 63;
    nfeat[k][c] = feats[((size_t)(b*N_ + kn[k]))*CIN + c];
  }
  if (tid < K_*3) {
    int k = tid / 3, j = tid - 3*k;
    rel[k][j] = xyz[((size_t)(b*N_ + kn[k]))*3 + j]
              - xyz[((size_t)(b*N_ + sidx))*3 + j];
  }
  __syncthreads();

  const int o = tid;

  // q[o] = s_feat . Wq[o,:]
  float q = 0.f;
  {
    const float4* a4 = (const float4*)sfeat;
    const float4* w4 = (const float4*)(Wq + o*CIN);
    #pragma unroll
    for (int i = 0; i < CIN/4; ++i) q += dot4(a4[i], w4[i]);
  }

  // pe hidden: thread j=o computes t1[k][j] for all k
  {
    float w0 = Wp1[o*3+0], w1 = Wp1[o*3+1], w2 = Wp1[o*3+2];
    #pragma unroll
    for (int k = 0; k < K_; ++k) {
      float d = rel[k][0]*w0 + rel[k][1]*w1 + rel[k][2]*w2;
      t1[k][o] = fmaxf(d, 0.f);
    }
  }
  __syncthreads();

  // pe[k][o] = t1[k,:] . Wp2[o,:]   (weight float4 loaded once, reused over k)
  float pe[K_];
  #pragma unroll
  for (int k = 0; k < K_; ++k) pe[k] = 0.f;
  {
    const float4* w4 = (const float4*)(Wp2 + o*COUT);
    #pragma unroll
    for (int i = 0; i < COUT/4; ++i) {
      float4 w = w4[i];
      #pragma unroll
      for (int k = 0; k < K_; ++k)
        pe[k] += dot4(((const float4*)t1[k])[i], w);
    }
  }

  // kk, v
  float kkv[K_], vv[K_];
  #pragma unroll
  for (int k = 0; k < K_; ++k) { kkv[k] = 0.f; vv[k] = 0.f; }
  {
    const float4* wk4 = (const float4*)(Wk + o*CIN);
    const float4* wv4 = (const float4*)(Wv + o*CIN);
    #pragma unroll
    for (int i = 0; i < CIN/4; ++i) {
      float4 wk = wk4[i], wv = wv4[i];
      #pragma unroll
      for (int k = 0; k < K_; ++k) {
        float4 nf = ((const float4*)nfeat[k])[i];
        kkv[k] += dot4(nf, wk);
        vv[k]  += dot4(nf, wv);
      }
    }
  }
  #pragma unroll
  for (int k = 0; k < K_; ++k) hsh[k][o] = q - kkv[k] + pe[k];
  __syncthreads();

  // attn hidden: a[k][m] = relu(h[k,:] . Wa1[m,:]); thread -> (m = tid&31, 4 k's)
  {
    const int m = tid & 31;
    const int kb = (tid >> 5) << 2;
    float a0 = 0.f, a1 = 0.f, a2 = 0.f, a3 = 0.f;
    const float4* wa4 = (const float4*)(Wa1 + m*COUT);
    const float4* h0 = (const float4*)hsh[kb + 0];
    const float4* h1 = (const float4*)hsh[kb + 1];
    const float4* h2 = (const float4*)hsh[kb + 2];
    const float4* h3 = (const float4*)hsh[kb + 3];
    #pragma unroll
    for (int i = 0; i < COUT/4; ++i) {
      float4 w = wa4[i];
      a0 += dot4(h0[i], w);
      a1 += dot4(h1[i], w);
      a2 += dot4(h2[i], w);
      a3 += dot4(h3[i], w);
    }
    ash[kb + 0][m] = fmaxf(a0, 0.f);
    ash[kb + 1][m] = fmaxf(a1, 0.f);
    ash[kb + 2][m] = fmaxf(a2, 0.f);
    ash[kb + 3][m] = fmaxf(a3, 0.f);
  }
  __syncthreads();

  // w[k][o] = a[k,:] . Wa2[o,:]
  float wv2[K_];
  #pragma unroll
  for (int k = 0; k < K_; ++k) wv2[k] = 0.f;
  {
    const float4* w4 = (const float4*)(Wa2 + o*MID_);
    #pragma unroll
    for (int i = 0; i < MID_/4; ++i) {
      float4 w = w4[i];
      #pragma unroll
      for (int k = 0; k < K_; ++k)
        wv2[k] += dot4(((const float4*)ash[k])[i], w);
    }
  }

  // softmax over k (thread-local), then out[o] = sum_k w*(v+pe)
  float mx = wv2[0];
  #pragma unroll
  for (int k = 1; k < K_; ++k) mx = fmaxf(mx, wv2[k]);
  float ssum = 0.f;
  #pragma unroll
  for (int k = 0; k < K_; ++k) { wv2[k] = __expf(wv2[k] - mx); ssum += wv2[k]; }
  float inv = 1.f / ssum;
  float outv = 0.f;
  #pragma unroll
  for (int k = 0; k < K_; ++k) outv += wv2[k] * (vv[k] + pe[k]);
  outv *= inv;
  vec[o] = outv;
  __syncthreads();

  // proj + residual
  float op = 0.f;
  {
    const float4* v4 = (const float4*)vec;
    const float4* w4 = (const float4*)(Wproj + o*COUT);
    #pragma unroll
    for (int i = 0; i < COUT/4; ++i) op += dot4(v4[i], w4[i]);
  }
  float res = 0.f;
  {
    const float4* a4 = (const float4*)sfeat;
    const float4* w4 = (const float4*)(Wres + o*CIN);
    #pragma unroll
    for (int i = 0; i < CIN/4; ++i) res += dot4(a4[i], w4[i]);
  }
  float y = op + res;

  // LayerNorm over 128 channels (2 waves)
  float p0 = y, p1 = y*y;
  #pragma unroll
  for (int off = 32; off > 0; off >>= 1) {
    p0 += __shfl_down(p0, off, 64);
    p1 += __shfl_down(p1, off, 64);
  }
  if ((tid & 63) == 0) { red[tid >> 6] = p0; red[2 + (tid >> 6)] = p1; }
  __syncthreads();
  float mean = (red[0] + red[1]) * (1.f/COUT);
  float var  = (red[2] + red[3]) * (1.f/COUT) - mean*mean;
  float z = (y - mean) * rsqrtf(var + EPS_) * ln_w[o] + ln_b[o];
  vec[o] = z;
  __syncthreads();

  // post conv (pre-GroupNorm) -> out_main
  float post = 0.f;
  {
    const float4* v4 = (const float4*)vec;
    const float4* w4 = (const float4*)(Wpost + o*COUT);
    #pragma unroll
    for (int i = 0; i < COUT/4; ++i) post += dot4(v4[i], w4[i]);
  }
  out_main[((size_t)(b*S_ + s))*COUT + o] = post;
}

// GroupNorm partial sums: grid = 32 (b,g) * 32 parts; each block: 256 s x 16 c
__global__ __launch_bounds__(256) void k_gn_partial(
    const float* __restrict__ x, double* __restrict__ part)
{
  const int bg = blockIdx.x >> 5;
  const int p  = blockIdx.x & 31;
  const int b = bg >> 3, g = bg & 7;
  const int tid = threadIdx.x;
  double s0 = 0.0, s1 = 0.0;
  const int sbase = p * 256;
  for (int i = tid; i < 256*16; i += 256) {
    int s = sbase + (i >> 4);
    int c = (g << 4) + (i & 15);
    float v = x[((size_t)(b*S_ + s))*COUT + c];
    s0 += v; s1 += (double)v * v;
  }
  __shared__ double sh0[256], sh1[256];
  sh0[tid] = s0; sh1[tid] = s1; __syncthreads();
  for (int off = 128; off > 0; off >>= 1) {
    if (tid < off) { sh0[tid] += sh0[tid+off]; sh1[tid] += sh1[tid+off]; }
    __syncthreads();
  }
  if (tid == 0) { part[blockIdx.x*2] = sh0[0]; part[blockIdx.x*2+1] = sh1[0]; }
}

__global__ void k_gn_finish(const double* __restrict__ part,
                            float* __restrict__ stats)
{
  const int bg = threadIdx.x;
  if (bg >= 32) return;
  double s0 = 0.0, s1 = 0.0;
  for (int p = 0; p < 32; ++p) {
    s0 += part[((size_t)bg*32 + p)*2];
    s1 += part[((size_t)bg*32 + p)*2 + 1];
  }
  const double n = (double)S_ * 16.0;
  double m = s0 / n;
  double var = s1 / n - m*m;
  stats[bg*2]     = (float)m;
  stats[bg*2 + 1] = (float)(1.0 / sqrt(var + 1e-5));
}

// normalize + affine + relu, in place on out_main
__global__ __launch_bounds__(256) void k_gn_apply(
    float* __restrict__ x, const float* __restrict__ stats,
    const float* __restrict__ gn_w, const float* __restrict__ gn_b)
{
  const int i = blockIdx.x * 256 + threadIdx.x;   // float4 index
  if (i >= B_*S_*(COUT/4)) return;
  const int c4 = i & 31;
  const int c = c4 * 4;
  const int g = c >> 4;
  const int b = i >> 18;                          // / (8192*32)
  const float m = stats[(b*8 + g)*2];
  const float r = stats[(b*8 + g)*2 + 1];
  float4 v = ((float4*)x)[i];
  v.x = fmaxf((v.x - m) * r * gn_w[c+0] + gn_b[c+0], 0.f);
  v.y = fmaxf((v.y - m) * r * gn_w[c+1] + gn_b[c+1], 0.f);
  v.z = fmaxf((v.z - m) * r * gn_w[c+2] + gn_b[c+2], 0.f);
  v.w = fmaxf((v.w - m) * r * gn_w[c+3] + gn_b[c+3], 0.f);
  ((float4*)x)[i] = v;
}

extern "C" void kernel_launch(void* const* d_in, const int* in_sizes, int n_in,
                              void* d_out, int out_size, void* d_ws, size_t ws_size,
                              hipStream_t stream) {
  const float* xyz     = (const float*)d_in[0];
  const float* feats   = (const float*)d_in[1];
  const int*   idx_fps = (const int*)d_in[2];
  const int*   idx_knn = (const int*)d_in[3];
  const float* Wq    = (const float*)d_in[4];
  const float* Wk    = (const float*)d_in[5];
  const float* Wv    = (const float*)d_in[6];
  const float* Wp1   = (const float*)d_in[7];
  const float* Wp2   = (const float*)d_in[8];
  const float* Wa1   = (const float*)d_in[9];
  const float* Wa2   = (const float*)d_in[10];
  const float* Wproj = (const float*)d_in[11];
  const float* ln_w  = (const float*)d_in[12];
  const float* ln_b  = (const float*)d_in[13];
  const float* Wres  = (const float*)d_in[14];
  const float* Wpost = (const float*)d_in[15];
  const float* gn_w  = (const float*)d_in[16];
  const float* gn_b  = (const float*)d_in[17];

  float* out      = (float*)d_out;
  float* out_xyz  = out;                       // (B,S,3)
  float* out_main = out + (size_t)B_*S_*3;     // (B,S,128)

  double* part = (double*)d_ws;                          // 1024*2 doubles
  float*  stats = (float*)((char*)d_ws + 1024*2*8);      // 32*2 floats

  k_point<<<dim3(B_*S_), dim3(128), 0, stream>>>(
      xyz, feats, idx_fps, idx_knn, Wq, Wk, Wv, Wp1, Wp2, Wa1, Wa2,
      Wproj, ln_w, ln_b, Wres, Wpost, out_xyz, out_main);

  k_gn_partial<<<dim3(32*32), dim3(256), 0, stream>>>(out_main, part);
  k_gn_finish<<<dim3(1), dim3(64), 0, stream>>>(part, stats);
  k_gn_apply<<<dim3((B_*S_*(COUT/4) + 255)/256), dim3(256), 0, stream>>>(
      out_main, stats, gn_w, gn_b);
}

// Round 2
// 261.781 us; speedup vs baseline: 14.1173x; 14.1173x over previous
//
#include <hip/hip_runtime.h>
#include <math.h>

#define B_ 4
#define N_ 32768
#define S_ 8192
#define K_ 16
#define CIN 64
#define COUT 128
#define MID_ 32
#define EPS_ 1e-5f
#define NTILE 2048   // (B_*S_)/16 epilogue tiles

typedef __attribute__((ext_vector_type(8))) short s16x8;
typedef __attribute__((ext_vector_type(4))) float f32x4;

// static scratch (written fully every call before being read)
__device__ ushort g_attn[(size_t)B_ * S_ * COUT];   // attn output, bf16, row-major
__device__ ushort g_sfeat[(size_t)B_ * S_ * CIN];   // gathered s_feat, bf16
__device__ float  g_part[NTILE * 8 * 2];            // GN partial sums per tile/group
__device__ float  g_stats[64];                      // GN mean/rstd per (b,g)

__device__ __forceinline__ ushort f2bf(float f) {
  uint u = __float_as_uint(f);
  uint r = (u + 0x7fffu + ((u >> 16) & 1u)) >> 16;   // RNE
  return (ushort)r;
}
__device__ __forceinline__ uint pk2(float lo, float hi) {
  return (uint)f2bf(lo) | ((uint)f2bf(hi) << 16);
}
__device__ __forceinline__ int4 pack8(float4 a, float4 b) {
  int4 o;
  o.x = pk2(a.x, a.y); o.y = pk2(a.z, a.w);
  o.z = pk2(b.x, b.y); o.w = pk2(b.z, b.w);
  return o;
}
__device__ __forceinline__ f32x4 mfma16(s16x8 a, s16x8 b, f32x4 c) {
  return __builtin_amdgcn_mfma_f32_16x16x32_bf16(a, b, c, 0, 0, 0);
}
// weight B-frag reads, swizzled rows of 256B / 128B
__device__ __forceinline__ s16x8 ldw256(const ushort* W, int row, int g) {
  return *(const s16x8*)((const char*)W + row * 256 + ((g ^ (row & 7)) << 4));
}
__device__ __forceinline__ s16x8 ldw128(const ushort* W, int row, int g) {
  return *(const s16x8*)((const char*)W + row * 128 + ((g ^ (row & 7)) << 4));
}
__device__ __forceinline__ s16x8 ldfrag_g8(const float* p) {
  float4 a = *(const float4*)p, b = *(const float4*)(p + 4);
  s16x8 f;
  f[0] = (short)f2bf(a.x); f[1] = (short)f2bf(a.y);
  f[2] = (short)f2bf(a.z); f[3] = (short)f2bf(a.w);
  f[4] = (short)f2bf(b.x); f[5] = (short)f2bf(b.y);
  f[6] = (short)f2bf(b.z); f[7] = (short)f2bf(b.w);
  return f;
}
// store a C tile (16x16 at n-tile t) as bf16 into a 16x128 swizzled buffer
__device__ __forceinline__ void st_tile(char* bufb, int t, f32x4 c, int l, int cq,
                                        bool dorelu) {
  int colp = (l & 14) + 16 * t;
  int g = colp >> 3;
  int off = (colp & 7) * 2;
  #pragma unroll
  for (int rr = 0; rr < 4; ++rr) {
    float v0 = dorelu ? fmaxf(c[rr], 0.f) : c[rr];
    float vo = __shfl_xor(v0, 1);
    uint pkv = (l & 1) ? pk2(vo, v0) : pk2(v0, vo);
    if ((rr >> 1) == (l & 1)) {
      int row = cq * 4 + rr;
      *(uint*)(bufb + row * 256 + ((g ^ (row & 7)) << 4) + off) = pkv;
    }
  }
}
// store 16x32 a1 tile (row stride 64B) with relu
__device__ __forceinline__ void st_a1(char* bufb, int t, f32x4 c, int l, int cq) {
  int colp = (l & 14) + 16 * t;   // 0..31
  int g = colp >> 3;              // 0..3
  int off = (colp & 7) * 2;
  #pragma unroll
  for (int rr = 0; rr < 4; ++rr) {
    float v0 = fmaxf(c[rr], 0.f);
    float vo = __shfl_xor(v0, 1);
    uint pkv = (l & 1) ? pk2(vo, v0) : pk2(v0, vo);
    if ((rr >> 1) == (l & 1)) {
      int row = cq * 4 + rr;
      *(uint*)(bufb + row * 64 + ((g ^ (row & 3)) << 4) + off) = pkv;
    }
  }
}

// ---------------- Kernel 1: attention core (per point, M = 16 neighbors) -----
__global__ __launch_bounds__(512, 2) void k_attn(
    const float* __restrict__ xyz, const float* __restrict__ feats,
    const int* __restrict__ idx_fps, const int* __restrict__ idx_knn,
    const float* __restrict__ Wq, const float* __restrict__ Wk,
    const float* __restrict__ Wv, const float* __restrict__ Wp1,
    const float* __restrict__ Wp2, const float* __restrict__ Wa1,
    const float* __restrict__ Wa2, float* __restrict__ out_xyz)
{
  __shared__ ushort lWqk[COUT * COUT];  // [Wq | -Wk], rows=out ch, 256B rows
  __shared__ ushort lWv[COUT * CIN];    // 128B rows
  __shared__ ushort lWp1[COUT * 8];     // padded to 8 k, linear 16B rows
  __shared__ ushort lWp2[COUT * COUT];
  __shared__ ushort sbuf[8 * 16 * COUT];  // 4KB per wave

  const int tid = threadIdx.x;
  const int w = tid >> 6, l = tid & 63;
  const int r = l & 15, cq = l >> 4;

  for (int i = tid; i < COUT * CIN; i += 512) {   // Wqk pairs: 128 rows x 64 pairs
    int row = i >> 6; int kp = (i & 63) * 2;
    float lo, hi;
    if (kp < CIN) { lo = Wq[row * CIN + kp]; hi = Wq[row * CIN + kp + 1]; }
    else { lo = -Wk[row * CIN + kp - CIN]; hi = -Wk[row * CIN + kp - CIN + 1]; }
    int g = kp >> 3;
    *(uint*)((char*)lWqk + row * 256 + ((g ^ (row & 7)) << 4) + (kp & 7) * 2) = pk2(lo, hi);
  }
  for (int i = tid; i < COUT * CIN / 2; i += 512) {
    int row = i >> 5; int kp = (i & 31) * 2;
    int g = kp >> 3;
    *(uint*)((char*)lWv + row * 128 + ((g ^ (row & 7)) << 4) + (kp & 7) * 2)
        = pk2(Wv[row * CIN + kp], Wv[row * CIN + kp + 1]);
  }
  { // Wp1 padded: 128 rows x 4 pairs = 512
    int row = tid >> 2; int kp = (tid & 3) * 2;
    float lo = (kp < 3) ? Wp1[row * 3 + kp] : 0.f;
    float hi = (kp + 1 < 3) ? Wp1[row * 3 + kp + 1] : 0.f;
    *(uint*)((char*)lWp1 + row * 16 + kp * 2) = pk2(lo, hi);
  }
  for (int i = tid; i < COUT * CIN; i += 512) {
    int row = i >> 6; int kp = (i & 63) * 2;
    int g = kp >> 3;
    *(uint*)((char*)lWp2 + row * 256 + ((g ^ (row & 7)) << 4) + (kp & 7) * 2)
        = pk2(Wp2[row * COUT + kp], Wp2[row * COUT + kp + 1]);
  }

  // register-resident B-frags for Wa1 (2 n-tiles x 4 k-steps) and Wa2 (8 n-tiles)
  s16x8 fWa1[2][4], fWa2[8];
  #pragma unroll
  for (int t = 0; t < 2; ++t)
    #pragma unroll
    for (int ks = 0; ks < 4; ++ks)
      fWa1[t][ks] = ldfrag_g8(Wa1 + (16 * t + r) * COUT + ks * 32 + cq * 8);
  #pragma unroll
  for (int t = 0; t < 8; ++t)
    fWa2[t] = ldfrag_g8(Wa2 + (16 * t + r) * MID_ + cq * 8);

  __syncthreads();

  char* bufb = (char*)(sbuf + w * 16 * COUT);

  #pragma unroll 1
  for (int i = 0; i < 16; ++i) {
    const int pid = (blockIdx.x * 8 + w) * 16 + i;
    const int b = pid >> 13;
    const int sidx = idx_fps[pid];
    const int nidx = idx_knn[(size_t)pid * K_ + r];
    const float* fs = feats + ((size_t)b * N_ + sidx) * CIN;
    const float* fn = feats + ((size_t)b * N_ + nidx) * CIN;

    // stage A = [s_feat | n_feat_r] row r (bf16, swizzled); also export s_feat
    #pragma unroll
    for (int j = 0; j < 2; ++j) {
      int g = cq * 2 + j;
      int4 pks = pack8(*(const float4*)(fs + g * 8), *(const float4*)(fs + g * 8 + 4));
      *(int4*)(bufb + r * 256 + ((g ^ (r & 7)) << 4)) = pks;
      if (r == 0) *(int4*)((char*)g_sfeat + (size_t)pid * 128 + g * 16) = pks;
      int g2 = 8 + g;
      *(int4*)(bufb + r * 256 + ((g2 ^ (r & 7)) << 4)) =
          pack8(*(const float4*)(fn + g * 8), *(const float4*)(fn + g * 8 + 4));
    }
    const float* xs = xyz + ((size_t)b * N_ + sidx) * 3;
    const float* xn = xyz + ((size_t)b * N_ + nidx) * 3;
    s16x8 fRel = {0, 0, 0, 0, 0, 0, 0, 0};
    if (cq == 0) {
      fRel[0] = (short)f2bf(xn[0] - xs[0]);
      fRel[1] = (short)f2bf(xn[1] - xs[1]);
      fRel[2] = (short)f2bf(xn[2] - xs[2]);
    }
    if (l < 3) out_xyz[(size_t)pid * 3 + l] = xs[l];

    // A-frags of staged [sfeat|nfeat]
    s16x8 fA[4];
    #pragma unroll
    for (int ks = 0; ks < 4; ++ks)
      fA[ks] = *(const s16x8*)(bufb + r * 256 + (((ks * 4 + cq) ^ (r & 7)) << 4));

    f32x4 qk[8], vv[8], pe[8];
    #pragma unroll
    for (int t = 0; t < 8; ++t) { qk[t] = (f32x4){0,0,0,0}; vv[t] = (f32x4){0,0,0,0}; }

    // qk = q - kk  (augmented GEMM, K=128)
    #pragma unroll
    for (int ks = 0; ks < 4; ++ks)
      #pragma unroll
      for (int t = 0; t < 8; ++t)
        qk[t] = mfma16(fA[ks], ldw256(lWqk, 16 * t + r, ks * 4 + cq), qk[t]);
    // v (K=64 over nfeat half)
    #pragma unroll
    for (int ks = 0; ks < 2; ++ks)
      #pragma unroll
      for (int t = 0; t < 8; ++t)
        vv[t] = mfma16(fA[2 + ks], ldw128(lWv, 16 * t + r, ks * 4 + cq), vv[t]);
    // t1 = relu(rel @ Wp1^T) -> buf
    #pragma unroll
    for (int t = 0; t < 8; ++t) {
      f32x4 z = {0, 0, 0, 0};
      f32x4 c = mfma16(fRel, *(const s16x8*)((const char*)lWp1 + (16 * t + r) * 16), z);
      st_tile(bufb, t, c, l, cq, true);
    }
    // pe = t1 @ Wp2^T
    s16x8 fT[4];
    #pragma unroll
    for (int ks = 0; ks < 4; ++ks)
      fT[ks] = *(const s16x8*)(bufb + r * 256 + (((ks * 4 + cq) ^ (r & 7)) << 4));
    #pragma unroll
    for (int t = 0; t < 8; ++t) pe[t] = (f32x4){0, 0, 0, 0};
    #pragma unroll
    for (int ks = 0; ks < 4; ++ks)
      #pragma unroll
      for (int t = 0; t < 8; ++t)
        pe[t] = mfma16(fT[ks], ldw256(lWp2, 16 * t + r, ks * 4 + cq), pe[t]);
    // h = qk + pe -> buf
    #pragma unroll
    for (int t = 0; t < 8; ++t) st_tile(bufb, t, qk[t] + pe[t], l, cq, false);
    // a1 = relu(h @ Wa1^T)
    s16x8 fH[4];
    #pragma unroll
    for (int ks = 0; ks < 4; ++ks)
      fH[ks] = *(const s16x8*)(bufb + r * 256 + (((ks * 4 + cq) ^ (r & 7)) << 4));
    f32x4 a1c[2];
    a1c[0] = (f32x4){0, 0, 0, 0}; a1c[1] = (f32x4){0, 0, 0, 0};
    #pragma unroll
    for (int ks = 0; ks < 4; ++ks)
      #pragma unroll
      for (int t = 0; t < 2; ++t)
        a1c[t] = mfma16(fH[ks], fWa1[t][ks], a1c[t]);
    st_a1(bufb, 0, a1c[0], l, cq);
    st_a1(bufb, 1, a1c[1], l, cq);
    // w = a1 @ Wa2^T
    s16x8 fA1 = *(const s16x8*)(bufb + r * 64 + ((cq ^ (r & 3)) << 4));
    f32x4 ww[8];
    #pragma unroll
    for (int t = 0; t < 8; ++t) {
      f32x4 z = {0, 0, 0, 0};
      ww[t] = mfma16(fA1, fWa2[t], z);
    }
    // softmax over neighbors (rows) + weighted sum of (v+pe)
    #pragma unroll
    for (int t = 0; t < 8; ++t) {
      float m = fmaxf(fmaxf(ww[t][0], ww[t][1]), fmaxf(ww[t][2], ww[t][3]));
      m = fmaxf(m, __shfl_xor(m, 16));
      m = fmaxf(m, __shfl_xor(m, 32));
      float e0 = __expf(ww[t][0] - m), e1 = __expf(ww[t][1] - m);
      float e2 = __expf(ww[t][2] - m), e3 = __expf(ww[t][3] - m);
      float ss = e0 + e1 + e2 + e3;
      ss += __shfl_xor(ss, 16);
      ss += __shfl_xor(ss, 32);
      float acc = e0 * (vv[t][0] + pe[t][0]) + e1 * (vv[t][1] + pe[t][1])
                + e2 * (vv[t][2] + pe[t][2]) + e3 * (vv[t][3] + pe[t][3]);
      acc += __shfl_xor(acc, 16);
      acc += __shfl_xor(acc, 32);
      float outv = acc / ss;
      // write attn bf16 (col pairs); t0-3 by cq0 even lanes, t4-7 by cq1
      float vo = __shfl_xor(outv, 1);
      uint pkv = (l & 1) ? pk2(vo, outv) : pk2(outv, vo);
      if ((l & 1) == 0 && cq == (t >> 2)) {
        int colp = (l & 14) + 16 * t;
        *(uint*)((char*)g_attn + (size_t)pid * 256 + colp * 2) = pkv;
      }
    }
  }
}

// ---------------- Kernel 2: proj + res + LN + post (M = 16 points) ----------
__global__ __launch_bounds__(512, 2) void k_post(
    const float* __restrict__ Wproj, const float* __restrict__ Wres,
    const float* __restrict__ Wpost, const float* __restrict__ ln_w,
    const float* __restrict__ ln_b, float* __restrict__ out_main)
{
  __shared__ ushort lWpj[COUT * COUT];
  __shared__ ushort lWrs[COUT * CIN];
  __shared__ ushort lWps[COUT * COUT];
  __shared__ float  llnw[COUT], llnb[COUT];
  __shared__ ushort sbuf[8 * 16 * COUT];

  const int tid = threadIdx.x;
  const int w = tid >> 6, l = tid & 63;
  const int r = l & 15, cq = l >> 4;

  for (int i = tid; i < COUT * CIN; i += 512) {
    int row = i >> 6; int kp = (i & 63) * 2;
    int g = kp >> 3;
    *(uint*)((char*)lWpj + row * 256 + ((g ^ (row & 7)) << 4) + (kp & 7) * 2)
        = pk2(Wproj[row * COUT + kp], Wproj[row * COUT + kp + 1]);
  }
  for (int i = tid; i < COUT * CIN / 2; i += 512) {
    int row = i >> 5; int kp = (i & 31) * 2;
    int g = kp >> 3;
    *(uint*)((char*)lWrs + row * 128 + ((g ^ (row & 7)) << 4) + (kp & 7) * 2)
        = pk2(Wres[row * CIN + kp], Wres[row * CIN + kp + 1]);
  }
  for (int i = tid; i < COUT * CIN; i += 512) {
    int row = i >> 6; int kp = (i & 63) * 2;
    int g = kp >> 3;
    *(uint*)((char*)lWps + row * 256 + ((g ^ (row & 7)) << 4) + (kp & 7) * 2)
        = pk2(Wpost[row * COUT + kp], Wpost[row * COUT + kp + 1]);
  }
  if (tid < COUT) { llnw[tid] = ln_w[tid]; llnb[tid] = ln_b[tid]; }
  __syncthreads();

  const int T = blockIdx.x * 8 + w;     // 16-point tile id
  char* bufb = (char*)(sbuf + w * 16 * COUT);

  f32x4 acc[8];
  #pragma unroll
  for (int t = 0; t < 8; ++t) acc[t] = (f32x4){0, 0, 0, 0};

  s16x8 fA[4];
  #pragma unroll
  for (int ks = 0; ks < 4; ++ks)
    fA[ks] = *(const s16x8*)(g_attn + ((size_t)T * 16 + r) * COUT + ks * 32 + cq * 8);
  #pragma unroll
  for (int ks = 0; ks < 4; ++ks)
    #pragma unroll
    for (int t = 0; t < 8; ++t)
      acc[t] = mfma16(fA[ks], ldw256(lWpj, 16 * t + r, ks * 4 + cq), acc[t]);

  s16x8 fS[2];
  #pragma unroll
  for (int ks = 0; ks < 2; ++ks)
    fS[ks] = *(const s16x8*)(g_sfeat + ((size_t)T * 16 + r) * CIN + ks * 32 + cq * 8);
  #pragma unroll
  for (int ks = 0; ks < 2; ++ks)
    #pragma unroll
    for (int t = 0; t < 8; ++t)
      acc[t] = mfma16(fS[ks], ldw128(lWrs, 16 * t + r, ks * 4 + cq), acc[t]);

  // LayerNorm per row (= point), cols across lanes&15 and 8 tiles
  #pragma unroll
  for (int rr = 0; rr < 4; ++rr) {
    float s1 = 0.f, s2 = 0.f;
    #pragma unroll
    for (int t = 0; t < 8; ++t) { float v = acc[t][rr]; s1 += v; s2 += v * v; }
    #pragma unroll
    for (int off = 1; off < 16; off <<= 1) {
      s1 += __shfl_xor(s1, off);
      s2 += __shfl_xor(s2, off);
    }
    float mu = s1 * (1.f / COUT);
    float rs = rsqrtf(s2 * (1.f / COUT) - mu * mu + EPS_);
    #pragma unroll
    for (int t = 0; t < 8; ++t) {
      int col = (l & 15) + 16 * t;
      acc[t][rr] = (acc[t][rr] - mu) * rs * llnw[col] + llnb[col];
    }
  }
  #pragma unroll
  for (int t = 0; t < 8; ++t) st_tile(bufb, t, acc[t], l, cq, false);

  // post conv GEMM
  s16x8 fZ[4];
  #pragma unroll
  for (int ks = 0; ks < 4; ++ks)
    fZ[ks] = *(const s16x8*)(bufb + r * 256 + (((ks * 4 + cq) ^ (r & 7)) << 4));
  f32x4 po[8];
  #pragma unroll
  for (int t = 0; t < 8; ++t) po[t] = (f32x4){0, 0, 0, 0};
  #pragma unroll
  for (int ks = 0; ks < 4; ++ks)
    #pragma unroll
    for (int t = 0; t < 8; ++t)
      po[t] = mfma16(fZ[ks], ldw256(lWps, 16 * t + r, ks * 4 + cq), po[t]);

  // write pre-GN post + per-tile GN partials (group = tile t)
  #pragma unroll
  for (int t = 0; t < 8; ++t) {
    float s1 = po[t][0] + po[t][1] + po[t][2] + po[t][3];
    float s2 = po[t][0] * po[t][0] + po[t][1] * po[t][1]
             + po[t][2] * po[t][2] + po[t][3] * po[t][3];
    #pragma unroll
    for (int off = 1; off < 64; off <<= 1) {
      s1 += __shfl_xor(s1, off);
      s2 += __shfl_xor(s2, off);
    }
    if (l == 0) {
      g_part[((size_t)T * 8 + t) * 2] = s1;
      g_part[((size_t)T * 8 + t) * 2 + 1] = s2;
    }
    #pragma unroll
    for (int rr = 0; rr < 4; ++rr) {
      int row = T * 16 + cq * 4 + rr;
      out_main[(size_t)row * COUT + (l & 15) + 16 * t] = po[t][rr];
    }
  }
}

// ---------------- GroupNorm finish + apply ----------------------------------
__global__ void k_gn_finish(void) {
  int bg = blockIdx.x;          // 0..31  (b*8+g)
  int b = bg >> 3, g = bg & 7;
  int t = threadIdx.x;          // 64
  float s1 = 0.f, s2 = 0.f;
  for (int i = t; i < 512; i += 64) {
    size_t T = (size_t)b * 512 + i;
    s1 += g_part[(T * 8 + g) * 2];
    s2 += g_part[(T * 8 + g) * 2 + 1];
  }
  #pragma unroll
  for (int off = 1; off < 64; off <<= 1) {
    s1 += __shfl_xor(s1, off);
    s2 += __shfl_xor(s2, off);
  }
  if (t == 0) {
    float n = (float)S_ * 16.f;
    float mu = s1 / n;
    float var = s2 / n - mu * mu;
    g_stats[bg * 2] = mu;
    g_stats[bg * 2 + 1] = rsqrtf(var + EPS_);
  }
}

__global__ __launch_bounds__(256) void k_gn_apply(
    float* __restrict__ x, const float* __restrict__ gn_w,
    const float* __restrict__ gn_b)
{
  const int i = blockIdx.x * 256 + threadIdx.x;   // float4 index
  if (i >= B_ * S_ * (COUT / 4)) return;
  const int c = (i & 31) * 4;
  const int g = c >> 4;
  const int b = i >> 18;
  const float m = g_stats[(b * 8 + g) * 2];
  const float rv = g_stats[(b * 8 + g) * 2 + 1];
  float4 v = ((float4*)x)[i];
  v.x = fmaxf((v.x - m) * rv * gn_w[c + 0] + gn_b[c + 0], 0.f);
  v.y = fmaxf((v.y - m) * rv * gn_w[c + 1] + gn_b[c + 1], 0.f);
  v.z = fmaxf((v.z - m) * rv * gn_w[c + 2] + gn_b[c + 2], 0.f);
  v.w = fmaxf((v.w - m) * rv * gn_w[c + 3] + gn_b[c + 3], 0.f);
  ((float4*)x)[i] = v;
}

extern "C" void kernel_launch(void* const* d_in, const int* in_sizes, int n_in,
                              void* d_out, int out_size, void* d_ws, size_t ws_size,
                              hipStream_t stream) {
  const float* xyz     = (const float*)d_in[0];
  const float* feats   = (const float*)d_in[1];
  const int*   idx_fps = (const int*)d_in[2];
  const int*   idx_knn = (const int*)d_in[3];
  const float* Wq    = (const float*)d_in[4];
  const float* Wk    = (const float*)d_in[5];
  const float* Wv    = (const float*)d_in[6];
  const float* Wp1   = (const float*)d_in[7];
  const float* Wp2   = (const float*)d_in[8];
  const float* Wa1   = (const float*)d_in[9];
  const float* Wa2   = (const float*)d_in[10];
  const float* Wproj = (const float*)d_in[11];
  const float* ln_w  = (const float*)d_in[12];
  const float* ln_b  = (const float*)d_in[13];
  const float* Wres  = (const float*)d_in[14];
  const float* Wpost = (const float*)d_in[15];
  const float* gn_w  = (const float*)d_in[16];
  const float* gn_b  = (const float*)d_in[17];

  float* out      = (float*)d_out;
  float* out_xyz  = out;
  float* out_main = out + (size_t)B_ * S_ * 3;

  k_attn<<<dim3(256), dim3(512), 0, stream>>>(
      xyz, feats, idx_fps, idx_knn, Wq, Wk, Wv, Wp1, Wp2, Wa1, Wa2, out_xyz);
  k_post<<<dim3(256), dim3(512), 0, stream>>>(
      Wproj, Wres, Wpost, ln_w, ln_b, out_main);
  k_gn_finish<<<dim3(32), dim3(64), 0, stream>>>();
  k_gn_apply<<<dim3((B_ * S_ * (COUT / 4) + 255) / 256), dim3(256), 0, stream>>>(
      out_main, gn_w, gn_b);
}

// Round 3
// 191.315 us; speedup vs baseline: 19.3171x; 1.3683x over previous
//
#include <hip/hip_runtime.h>
#include <hip/hip_bf16.h>
#include <math.h>

#define B_ 4
#define N_ 32768
#define S_ 8192
#define K_ 16
#define CIN 64
#define COUT 128
#define MID_ 32
#define EPS_ 1e-5f
#define NTILE 2048   // (B_*S_)/16 epilogue tiles

typedef __attribute__((ext_vector_type(8))) short s16x8;
typedef __attribute__((ext_vector_type(4))) float f32x4;

// static scratch (written fully every call before being read)
__device__ ushort g_attn[(size_t)B_ * S_ * COUT];   // attn output, bf16, row-major
__device__ ushort g_sfeat[(size_t)B_ * S_ * CIN];   // gathered s_feat, bf16
__device__ float  g_part[NTILE * 8 * 2];            // GN partial sums per tile/group
__device__ float  g_stats[64];                      // GN mean/rstd per (b,g)

// hardware bf16 converts (v_cvt_pk_bf16_f32)
__device__ __forceinline__ uint pk2(float lo, float hi) {
  __hip_bfloat162 h = __float22bfloat162_rn(make_float2(lo, hi));
  return *(uint*)&h;
}
__device__ __forceinline__ ushort f2bf(float f) {
  __hip_bfloat16 h = __float2bfloat16(f);
  return *(ushort*)&h;
}
__device__ __forceinline__ int4 pack8(float4 a, float4 b) {
  int4 o;
  o.x = pk2(a.x, a.y); o.y = pk2(a.z, a.w);
  o.z = pk2(b.x, b.y); o.w = pk2(b.z, b.w);
  return o;
}
__device__ __forceinline__ f32x4 mfma16(s16x8 a, s16x8 b, f32x4 c) {
  return __builtin_amdgcn_mfma_f32_16x16x32_bf16(a, b, c, 0, 0, 0);
}
// weight B-frag reads, swizzled rows of 256B / 128B
__device__ __forceinline__ s16x8 ldw256(const ushort* W, int row, int g) {
  return *(const s16x8*)((const char*)W + row * 256 + ((g ^ (row & 7)) << 4));
}
__device__ __forceinline__ s16x8 ldw128(const ushort* W, int row, int g) {
  return *(const s16x8*)((const char*)W + row * 128 + ((g ^ (row & 7)) << 4));
}
__device__ __forceinline__ s16x8 ldfrag_g8(const float* p) {
  float4 a = *(const float4*)p, b = *(const float4*)(p + 4);
  union { int4 i; s16x8 s; } u;
  u.i = pack8(a, b);
  return u.s;
}
// store a C tile (16 cols at n-tile t) bf16 into 16x128 swizzled buffer, b16 writes
__device__ __forceinline__ void st16(char* bufb, int t, f32x4 c, int l, int cq,
                                     bool dorelu) {
  const int colp = (l & 15) + 16 * t;
  const int g = colp >> 3;
  const int off = (colp & 7) * 2;
  #pragma unroll
  for (int rr = 0; rr < 4; ++rr) {
    const int row = cq * 4 + rr;
    float v = dorelu ? fmaxf(c[rr], 0.f) : c[rr];
    *(ushort*)(bufb + row * 256 + ((g ^ (row & 7)) << 4) + off) = f2bf(v);
  }
}
// store 16x32 a1 tile (row stride 64B) with relu, b16 writes
__device__ __forceinline__ void st16_a1(char* bufb, int t, f32x4 c, int l, int cq) {
  const int colp = (l & 15) + 16 * t;   // 0..31
  const int g = colp >> 3;              // 0..3
  const int off = (colp & 7) * 2;
  #pragma unroll
  for (int rr = 0; rr < 4; ++rr) {
    const int row = cq * 4 + rr;
    *(ushort*)(bufb + row * 64 + ((g ^ (row & 3)) << 4) + off) =
        f2bf(fmaxf(c[rr], 0.f));
  }
}

// ---------------- Kernel 1: attention core (per point, M = 16 neighbors) -----
__global__ __launch_bounds__(512, 2) void k_attn(
    const float* __restrict__ xyz, const float* __restrict__ feats,
    const int* __restrict__ idx_fps, const int* __restrict__ idx_knn,
    const float* __restrict__ Wq, const float* __restrict__ Wk,
    const float* __restrict__ Wv, const float* __restrict__ Wp1,
    const float* __restrict__ Wp2, const float* __restrict__ Wa1,
    const float* __restrict__ Wa2, float* __restrict__ out_xyz)
{
  __shared__ ushort lWk[COUT * CIN];    // -Wk, 128B rows, swizzled
  __shared__ ushort lWv[COUT * CIN];    // 128B rows
  __shared__ ushort lWp1[COUT * 8];     // padded to 8 k, linear 16B rows
  __shared__ ushort lWp2[COUT * COUT];  // 256B rows
  __shared__ ushort sbuf[8 * 16 * COUT];  // 4KB per wave

  const int tid = threadIdx.x;
  const int w = tid >> 6, l = tid & 63;
  const int r = l & 15, cq = l >> 4;

  for (int i = tid; i < COUT * CIN / 2; i += 512) {   // -Wk
    int row = i >> 5; int kp = (i & 31) * 2;
    int g = kp >> 3;
    *(uint*)((char*)lWk + row * 128 + ((g ^ (row & 7)) << 4) + (kp & 7) * 2)
        = pk2(-Wk[row * CIN + kp], -Wk[row * CIN + kp + 1]);
  }
  for (int i = tid; i < COUT * CIN / 2; i += 512) {
    int row = i >> 5; int kp = (i & 31) * 2;
    int g = kp >> 3;
    *(uint*)((char*)lWv + row * 128 + ((g ^ (row & 7)) << 4) + (kp & 7) * 2)
        = pk2(Wv[row * CIN + kp], Wv[row * CIN + kp + 1]);
  }
  { // Wp1 padded: 128 rows x 4 pairs = 512
    int row = tid >> 2; int kp = (tid & 3) * 2;
    float lo = (kp < 3) ? Wp1[row * 3 + kp] : 0.f;
    float hi = (kp + 1 < 3) ? Wp1[row * 3 + kp + 1] : 0.f;
    *(uint*)((char*)lWp1 + row * 16 + kp * 2) = pk2(lo, hi);
  }
  for (int i = tid; i < COUT * CIN; i += 512) {
    int row = i >> 6; int kp = (i & 63) * 2;
    int g = kp >> 3;
    *(uint*)((char*)lWp2 + row * 256 + ((g ^ (row & 7)) << 4) + (kp & 7) * 2)
        = pk2(Wp2[row * COUT + kp], Wp2[row * COUT + kp + 1]);
  }

  // register-resident B-frags for Wa1 (2 n-tiles x 4 k-steps) and Wa2 (8 n-tiles)
  s16x8 fWa1[2][4], fWa2[8];
  #pragma unroll
  for (int t = 0; t < 2; ++t)
    #pragma unroll
    for (int ks = 0; ks < 4; ++ks)
      fWa1[t][ks] = ldfrag_g8(Wa1 + (16 * t + r) * COUT + ks * 32 + cq * 8);
  #pragma unroll
  for (int t = 0; t < 8; ++t)
    fWa2[t] = ldfrag_g8(Wa2 + (16 * t + r) * MID_ + cq * 8);

  __syncthreads();

  char* bufb = (char*)(sbuf + w * 16 * COUT);
  const int pid0 = (blockIdx.x * 8 + w) * 16;

  // ---- per-wave prologue: stage sfeat (row = point), q GEMM for 16 points ----
  {
    const int p = pid0 + r;
    const int bb = p >> 13;
    const int si = idx_fps[p];
    const float* fs = feats + ((size_t)bb * N_ + si) * CIN;
    #pragma unroll
    for (int j = 0; j < 2; ++j) {
      int g = cq * 2 + j;
      int4 pks = pack8(*(const float4*)(fs + g * 8), *(const float4*)(fs + g * 8 + 4));
      *(int4*)(bufb + r * 128 + ((g ^ (r & 7)) << 4)) = pks;
      *(int4*)((char*)g_sfeat + (size_t)p * 128 + g * 16) = pks;
    }
    if (l < 48) {
      int pi = l / 3, j = l - pi * 3;
      int pp = pid0 + pi;
      out_xyz[(size_t)pp * 3 + j] =
          xyz[((size_t)(pp >> 13) * N_ + idx_fps[pp]) * 3 + j];
    }
  }
  f32x4 q[8];
  #pragma unroll
  for (int t = 0; t < 8; ++t) q[t] = (f32x4){0, 0, 0, 0};
  {
    s16x8 fS[2];
    #pragma unroll
    for (int ks = 0; ks < 2; ++ks)
      fS[ks] = *(const s16x8*)(bufb + r * 128 + (((ks * 4 + cq) ^ (r & 7)) << 4));
    #pragma unroll
    for (int ks = 0; ks < 2; ++ks)
      #pragma unroll
      for (int t = 0; t < 8; ++t)
        q[t] = mfma16(fS[ks],
                      ldfrag_g8(Wq + (16 * t + r) * CIN + ks * 32 + cq * 8), q[t]);
  }

  // ---- per-point loop ----
  #pragma unroll 1
  for (int i = 0; i < 16; ++i) {
    const int pid = pid0 + i;
    const int b = pid >> 13;
    const int nidx = idx_knn[(size_t)pid * K_ + r];
    const float* fn = feats + ((size_t)b * N_ + nidx) * CIN;

    // stage A = n_feat (16 x 64 bf16, 128B swizzled rows)
    #pragma unroll
    for (int j = 0; j < 2; ++j) {
      int g = cq * 2 + j;
      *(int4*)(bufb + r * 128 + ((g ^ (r & 7)) << 4)) =
          pack8(*(const float4*)(fn + g * 8), *(const float4*)(fn + g * 8 + 4));
    }
    s16x8 fRel = {0, 0, 0, 0, 0, 0, 0, 0};
    if (cq == 0) {
      const float* xs = xyz + ((size_t)b * N_ + idx_fps[pid]) * 3;
      const float* xn = xyz + ((size_t)b * N_ + nidx) * 3;
      fRel[0] = (short)f2bf(xn[0] - xs[0]);
      fRel[1] = (short)f2bf(xn[1] - xs[1]);
      fRel[2] = (short)f2bf(xn[2] - xs[2]);
    }

    s16x8 fA[2];
    #pragma unroll
    for (int ks = 0; ks < 2; ++ks)
      fA[ks] = *(const s16x8*)(bufb + r * 128 + (((ks * 4 + cq) ^ (r & 7)) << 4));

    f32x4 kk[8], vv[8], pe[8];
    #pragma unroll
    for (int t = 0; t < 8; ++t) { kk[t] = (f32x4){0,0,0,0}; vv[t] = (f32x4){0,0,0,0}; }

    // kk = -(nfeat @ Wk^T)   (K=64)
    #pragma unroll
    for (int ks = 0; ks < 2; ++ks)
      #pragma unroll
      for (int t = 0; t < 8; ++t)
        kk[t] = mfma16(fA[ks], ldw128(lWk, 16 * t + r, ks * 4 + cq), kk[t]);
    // v
    #pragma unroll
    for (int ks = 0; ks < 2; ++ks)
      #pragma unroll
      for (int t = 0; t < 8; ++t)
        vv[t] = mfma16(fA[ks], ldw128(lWv, 16 * t + r, ks * 4 + cq), vv[t]);

    // t1 = relu(rel @ Wp1^T) -> buf
    #pragma unroll
    for (int t = 0; t < 8; ++t) {
      f32x4 z = {0, 0, 0, 0};
      f32x4 c = mfma16(fRel, *(const s16x8*)((const char*)lWp1 + (16 * t + r) * 16), z);
      st16(bufb, t, c, l, cq, true);
    }
    // pe = t1 @ Wp2^T
    s16x8 fT[4];
    #pragma unroll
    for (int ks = 0; ks < 4; ++ks)
      fT[ks] = *(const s16x8*)(bufb + r * 256 + (((ks * 4 + cq) ^ (r & 7)) << 4));
    #pragma unroll
    for (int t = 0; t < 8; ++t) pe[t] = (f32x4){0, 0, 0, 0};
    #pragma unroll
    for (int ks = 0; ks < 4; ++ks)
      #pragma unroll
      for (int t = 0; t < 8; ++t)
        pe[t] = mfma16(fT[ks], ldw256(lWp2, 16 * t + r, ks * 4 + cq), pe[t]);

    // h = q - kk + pe -> buf  (q broadcast: row i of q C-frag)
    const int ii = i & 3, iq = i >> 2;
    #pragma unroll
    for (int t = 0; t < 8; ++t) {
      float qsel = ii == 0 ? q[t][0] : ii == 1 ? q[t][1] : ii == 2 ? q[t][2] : q[t][3];
      float qv = __shfl(qsel, (iq << 4) + (l & 15));
      f32x4 h;
      #pragma unroll
      for (int rr = 0; rr < 4; ++rr) h[rr] = qv + kk[t][rr] + pe[t][rr];
      st16(bufb, t, h, l, cq, false);
    }
    // a1 = relu(h @ Wa1^T)
    s16x8 fH[4];
    #pragma unroll
    for (int ks = 0; ks < 4; ++ks)
      fH[ks] = *(const s16x8*)(bufb + r * 256 + (((ks * 4 + cq) ^ (r & 7)) << 4));
    f32x4 a1c[2];
    a1c[0] = (f32x4){0, 0, 0, 0}; a1c[1] = (f32x4){0, 0, 0, 0};
    #pragma unroll
    for (int ks = 0; ks < 4; ++ks)
      #pragma unroll
      for (int t = 0; t < 2; ++t)
        a1c[t] = mfma16(fH[ks], fWa1[t][ks], a1c[t]);
    st16_a1(bufb, 0, a1c[0], l, cq);
    st16_a1(bufb, 1, a1c[1], l, cq);
    // w = a1 @ Wa2^T
    s16x8 fA1 = *(const s16x8*)(bufb + r * 64 + ((cq ^ (r & 3)) << 4));
    f32x4 ww[8];
    #pragma unroll
    for (int t = 0; t < 8; ++t) {
      f32x4 z = {0, 0, 0, 0};
      ww[t] = mfma16(fA1, fWa2[t], z);
    }
    // softmax over neighbors (rows) + weighted sum of (v+pe)
    #pragma unroll
    for (int t = 0; t < 8; ++t) {
      float m = fmaxf(fmaxf(ww[t][0], ww[t][1]), fmaxf(ww[t][2], ww[t][3]));
      m = fmaxf(m, __shfl_xor(m, 16));
      m = fmaxf(m, __shfl_xor(m, 32));
      float e0 = __expf(ww[t][0] - m), e1 = __expf(ww[t][1] - m);
      float e2 = __expf(ww[t][2] - m), e3 = __expf(ww[t][3] - m);
      float ss = e0 + e1 + e2 + e3;
      ss += __shfl_xor(ss, 16);
      ss += __shfl_xor(ss, 32);
      float acc = e0 * (vv[t][0] + pe[t][0]) + e1 * (vv[t][1] + pe[t][1])
                + e2 * (vv[t][2] + pe[t][2]) + e3 * (vv[t][3] + pe[t][3]);
      acc += __shfl_xor(acc, 16);
      acc += __shfl_xor(acc, 32);
      float outv = acc / ss;
      if (cq == (t >> 2)) {
        int colp = (l & 15) + 16 * t;
        *(ushort*)((char*)g_attn + (size_t)pid * 256 + colp * 2) = f2bf(outv);
      }
    }
  }
}

// ---------------- Kernel 2: proj + res + LN + post (M = 16 points) ----------
__global__ __launch_bounds__(512, 2) void k_post(
    const float* __restrict__ Wproj, const float* __restrict__ Wres,
    const float* __restrict__ Wpost, const float* __restrict__ ln_w,
    const float* __restrict__ ln_b, float* __restrict__ out_main)
{
  __shared__ ushort lWpj[COUT * COUT];
  __shared__ ushort lWrs[COUT * CIN];
  __shared__ ushort lWps[COUT * COUT];
  __shared__ float  llnw[COUT], llnb[COUT];
  __shared__ ushort sbuf[8 * 16 * COUT];

  const int tid = threadIdx.x;
  const int w = tid >> 6, l = tid & 63;
  const int r = l & 15, cq = l >> 4;

  for (int i = tid; i < COUT * CIN; i += 512) {
    int row = i >> 6; int kp = (i & 63) * 2;
    int g = kp >> 3;
    *(uint*)((char*)lWpj + row * 256 + ((g ^ (row & 7)) << 4) + (kp & 7) * 2)
        = pk2(Wproj[row * COUT + kp], Wproj[row * COUT + kp + 1]);
  }
  for (int i = tid; i < COUT * CIN / 2; i += 512) {
    int row = i >> 5; int kp = (i & 31) * 2;
    int g = kp >> 3;
    *(uint*)((char*)lWrs + row * 128 + ((g ^ (row & 7)) << 4) + (kp & 7) * 2)
        = pk2(Wres[row * CIN + kp], Wres[row * CIN + kp + 1]);
  }
  for (int i = tid; i < COUT * CIN; i += 512) {
    int row = i >> 6; int kp = (i & 63) * 2;
    int g = kp >> 3;
    *(uint*)((char*)lWps + row * 256 + ((g ^ (row & 7)) << 4) + (kp & 7) * 2)
        = pk2(Wpost[row * COUT + kp], Wpost[row * COUT + kp + 1]);
  }
  if (tid < COUT) { llnw[tid] = ln_w[tid]; llnb[tid] = ln_b[tid]; }
  __syncthreads();

  const int T = blockIdx.x * 8 + w;     // 16-point tile id
  char* bufb = (char*)(sbuf + w * 16 * COUT);

  f32x4 acc[8];
  #pragma unroll
  for (int t = 0; t < 8; ++t) acc[t] = (f32x4){0, 0, 0, 0};

  s16x8 fA[4];
  #pragma unroll
  for (int ks = 0; ks < 4; ++ks)
    fA[ks] = *(const s16x8*)(g_attn + ((size_t)T * 16 + r) * COUT + ks * 32 + cq * 8);
  #pragma unroll
  for (int ks = 0; ks < 4; ++ks)
    #pragma unroll
    for (int t = 0; t < 8; ++t)
      acc[t] = mfma16(fA[ks], ldw256(lWpj, 16 * t + r, ks * 4 + cq), acc[t]);

  s16x8 fS[2];
  #pragma unroll
  for (int ks = 0; ks < 2; ++ks)
    fS[ks] = *(const s16x8*)(g_sfeat + ((size_t)T * 16 + r) * CIN + ks * 32 + cq * 8);
  #pragma unroll
  for (int ks = 0; ks < 2; ++ks)
    #pragma unroll
    for (int t = 0; t < 8; ++t)
      acc[t] = mfma16(fS[ks], ldw128(lWrs, 16 * t + r, ks * 4 + cq), acc[t]);

  // LayerNorm per row (= point)
  #pragma unroll
  for (int rr = 0; rr < 4; ++rr) {
    float s1 = 0.f, s2 = 0.f;
    #pragma unroll
    for (int t = 0; t < 8; ++t) { float v = acc[t][rr]; s1 += v; s2 += v * v; }
    #pragma unroll
    for (int off = 1; off < 16; off <<= 1) {
      s1 += __shfl_xor(s1, off);
      s2 += __shfl_xor(s2, off);
    }
    float mu = s1 * (1.f / COUT);
    float rs = rsqrtf(s2 * (1.f / COUT) - mu * mu + EPS_);
    #pragma unroll
    for (int t = 0; t < 8; ++t) {
      int col = (l & 15) + 16 * t;
      acc[t][rr] = (acc[t][rr] - mu) * rs * llnw[col] + llnb[col];
    }
  }
  #pragma unroll
  for (int t = 0; t < 8; ++t) st16(bufb, t, acc[t], l, cq, false);

  // post conv GEMM
  s16x8 fZ[4];
  #pragma unroll
  for (int ks = 0; ks < 4; ++ks)
    fZ[ks] = *(const s16x8*)(bufb + r * 256 + (((ks * 4 + cq) ^ (r & 7)) << 4));
  f32x4 po[8];
  #pragma unroll
  for (int t = 0; t < 8; ++t) po[t] = (f32x4){0, 0, 0, 0};
  #pragma unroll
  for (int ks = 0; ks < 4; ++ks)
    #pragma unroll
    for (int t = 0; t < 8; ++t)
      po[t] = mfma16(fZ[ks], ldw256(lWps, 16 * t + r, ks * 4 + cq), po[t]);

  // write pre-GN post + per-tile GN partials (group = tile t)
  #pragma unroll
  for (int t = 0; t < 8; ++t) {
    float s1 = po[t][0] + po[t][1] + po[t][2] + po[t][3];
    float s2 = po[t][0] * po[t][0] + po[t][1] * po[t][1]
             + po[t][2] * po[t][2] + po[t][3] * po[t][3];
    #pragma unroll
    for (int off = 1; off < 64; off <<= 1) {
      s1 += __shfl_xor(s1, off);
      s2 += __shfl_xor(s2, off);
    }
    if (l == 0) {
      g_part[((size_t)T * 8 + t) * 2] = s1;
      g_part[((size_t)T * 8 + t) * 2 + 1] = s2;
    }
    #pragma unroll
    for (int rr = 0; rr < 4; ++rr) {
      int row = T * 16 + cq * 4 + rr;
      out_main[(size_t)row * COUT + (l & 15) + 16 * t] = po[t][rr];
    }
  }
}

// ---------------- GroupNorm finish + apply ----------------------------------
__global__ void k_gn_finish(void) {
  int bg = blockIdx.x;          // 0..31  (b*8+g)
  int b = bg >> 3, g = bg & 7;
  int t = threadIdx.x;          // 64
  float s1 = 0.f, s2 = 0.f;
  for (int i = t; i < 512; i += 64) {
    size_t T = (size_t)b * 512 + i;
    s1 += g_part[(T * 8 + g) * 2];
    s2 += g_part[(T * 8 + g) * 2 + 1];
  }
  #pragma unroll
  for (int off = 1; off < 64; off <<= 1) {
    s1 += __shfl_xor(s1, off);
    s2 += __shfl_xor(s2, off);
  }
  if (t == 0) {
    float n = (float)S_ * 16.f;
    float mu = s1 / n;
    float var = s2 / n - mu * mu;
    g_stats[bg * 2] = mu;
    g_stats[bg * 2 + 1] = rsqrtf(var + EPS_);
  }
}

__global__ __launch_bounds__(256) void k_gn_apply(
    float* __restrict__ x, const float* __restrict__ gn_w,
    const float* __restrict__ gn_b)
{
  const int i = blockIdx.x * 256 + threadIdx.x;   // float4 index
  if (i >= B_ * S_ * (COUT / 4)) return;
  const int c = (i & 31) * 4;
  const int g = c >> 4;
  const int b = i >> 18;
  const float m = g_stats[(b * 8 + g) * 2];
  const float rv = g_stats[(b * 8 + g) * 2 + 1];
  float4 v = ((float4*)x)[i];
  v.x = fmaxf((v.x - m) * rv * gn_w[c + 0] + gn_b[c + 0], 0.f);
  v.y = fmaxf((v.y - m) * rv * gn_w[c + 1] + gn_b[c + 1], 0.f);
  v.z = fmaxf((v.z - m) * rv * gn_w[c + 2] + gn_b[c + 2], 0.f);
  v.w = fmaxf((v.w - m) * rv * gn_w[c + 3] + gn_b[c + 3], 0.f);
  ((float4*)x)[i] = v;
}

extern "C" void kernel_launch(void* const* d_in, const int* in_sizes, int n_in,
                              void* d_out, int out_size, void* d_ws, size_t ws_size,
                              hipStream_t stream) {
  const float* xyz     = (const float*)d_in[0];
  const float* feats   = (const float*)d_in[1];
  const int*   idx_fps = (const int*)d_in[2];
  const int*   idx_knn = (const int*)d_in[3];
  const float* Wq    = (const float*)d_in[4];
  const float* Wk    = (const float*)d_in[5];
  const float* Wv    = (const float*)d_in[6];
  const float* Wp1   = (const float*)d_in[7];
  const float* Wp2   = (const float*)d_in[8];
  const float* Wa1   = (const float*)d_in[9];
  const float* Wa2   = (const float*)d_in[10];
  const float* Wproj = (const float*)d_in[11];
  const float* ln_w  = (const float*)d_in[12];
  const float* ln_b  = (const float*)d_in[13];
  const float* Wres  = (const float*)d_in[14];
  const float* Wpost = (const float*)d_in[15];
  const float* gn_w  = (const float*)d_in[16];
  const float* gn_b  = (const float*)d_in[17];

  float* out      = (float*)d_out;
  float* out_xyz  = out;
  float* out_main = out + (size_t)B_ * S_ * 3;

  k_attn<<<dim3(256), dim3(512), 0, stream>>>(
      xyz, feats, idx_fps, idx_knn, Wq, Wk, Wv, Wp1, Wp2, Wa1, Wa2, out_xyz);
  k_post<<<dim3(256), dim3(512), 0, stream>>>(
      Wproj, Wres, Wpost, ln_w, ln_b, out_main);
  k_gn_finish<<<dim3(32), dim3(64), 0, stream>>>();
  k_gn_apply<<<dim3((B_ * S_ * (COUT / 4) + 255) / 256), dim3(256), 0, stream>>>(
      out_main, gn_w, gn_b);
}

// Round 4
// 140.539 us; speedup vs baseline: 26.2962x; 1.3613x over previous
//
#include <hip/hip_runtime.h>
#include <hip/hip_bf16.h>
#include <math.h>

#define B_ 4
#define N_ 32768
#define S_ 8192
#define K_ 16
#define CIN 64
#define COUT 128
#define MID_ 32
#define EPS_ 1e-5f
#define NTILE 2048   // (B_*S_)/16 epilogue tiles

typedef __attribute__((ext_vector_type(8))) short s16x8;
typedef __attribute__((ext_vector_type(4))) float f32x4;

// static scratch (written fully every call before being read)
__device__ ushort g_attn[(size_t)B_ * S_ * COUT];   // attn output, bf16, row-major
__device__ ushort g_sfeat[(size_t)B_ * S_ * CIN];   // gathered s_feat, bf16
__device__ float  g_part[NTILE * 8 * 2];            // GN partial sums per tile/group
__device__ float  g_stats[64];                      // GN mean/rstd per (b,g)
// fused weights: [0,2048) Wqa1 32x64; [2048,4096) Wka1 32x64; [4096,8192) Wpa1 32x128
__device__ float  g_fw[8192];

// hardware bf16 converts (v_cvt_pk_bf16_f32)
__device__ __forceinline__ uint pk2(float lo, float hi) {
  __hip_bfloat162 h = __float22bfloat162_rn(make_float2(lo, hi));
  return *(uint*)&h;
}
__device__ __forceinline__ ushort f2bf(float f) {
  __hip_bfloat16 h = __float2bfloat16(f);
  return *(ushort*)&h;
}
__device__ __forceinline__ int4 pack8(float4 a, float4 b) {
  int4 o;
  o.x = pk2(a.x, a.y); o.y = pk2(a.z, a.w);
  o.z = pk2(b.x, b.y); o.w = pk2(b.z, b.w);
  return o;
}
__device__ __forceinline__ f32x4 mfma16(s16x8 a, s16x8 b, f32x4 c) {
  return __builtin_amdgcn_mfma_f32_16x16x32_bf16(a, b, c, 0, 0, 0);
}
// weight B-frag reads, swizzled rows of 256B / 128B
__device__ __forceinline__ s16x8 ldw256(const ushort* W, int row, int g) {
  return *(const s16x8*)((const char*)W + row * 256 + ((g ^ (row & 7)) << 4));
}
__device__ __forceinline__ s16x8 ldw128(const ushort* W, int row, int g) {
  return *(const s16x8*)((const char*)W + row * 128 + ((g ^ (row & 7)) << 4));
}
__device__ __forceinline__ s16x8 ldfrag_g8(const float* p) {
  float4 a = *(const float4*)p, b = *(const float4*)(p + 4);
  union { int4 i; s16x8 s; } u;
  u.i = pack8(a, b);
  return u.s;
}
// store a C tile (16 cols at n-tile t) bf16 into 16x128 swizzled buffer, b16 writes
__device__ __forceinline__ void st16(char* bufb, int t, f32x4 c, int l, int cq,
                                     bool dorelu) {
  const int colp = (l & 15) + 16 * t;
  const int g = colp >> 3;
  const int off = (colp & 7) * 2;
  #pragma unroll
  for (int rr = 0; rr < 4; ++rr) {
    const int row = cq * 4 + rr;
    float v = dorelu ? fmaxf(c[rr], 0.f) : c[rr];
    *(ushort*)(bufb + row * 256 + ((g ^ (row & 7)) << 4) + off) = f2bf(v);
  }
}
// store 16x32 a1 tile (row stride 64B) with relu, b16 writes
__device__ __forceinline__ void st16_a1(char* bufb, int t, f32x4 c, int l, int cq) {
  const int colp = (l & 15) + 16 * t;   // 0..31
  const int g = colp >> 3;              // 0..3
  const int off = (colp & 7) * 2;
  #pragma unroll
  for (int rr = 0; rr < 4; ++rr) {
    const int row = cq * 4 + rr;
    *(ushort*)(bufb + row * 64 + ((g ^ (row & 3)) << 4) + off) =
        f2bf(fmaxf(c[rr], 0.f));
  }
}

// ---------------- Kernel 0: fused weights  Wa1 @ {Wq, Wk, Wp2} ---------------
__global__ __launch_bounds__(256) void k_fuse(
    const float* __restrict__ Wq, const float* __restrict__ Wk,
    const float* __restrict__ Wp2, const float* __restrict__ Wa1)
{
  const int t = blockIdx.x * 256 + threadIdx.x;   // 0..8191
  if (t < 2048) {
    int m = t >> 6, c = t & 63;
    float s = 0.f;
    for (int o = 0; o < COUT; ++o) s += Wa1[m * COUT + o] * Wq[o * CIN + c];
    g_fw[t] = s;
  } else if (t < 4096) {
    int u = t - 2048;
    int m = u >> 6, c = u & 63;
    float s = 0.f;
    for (int o = 0; o < COUT; ++o) s += Wa1[m * COUT + o] * Wk[o * CIN + c];
    g_fw[t] = s;
  } else {
    int u = t - 4096;
    int m = u >> 7, c = u & 127;
    float s = 0.f;
    for (int o = 0; o < COUT; ++o) s += Wa1[m * COUT + o] * Wp2[o * COUT + c];
    g_fw[t] = s;
  }
}

// ---------------- Kernel 1: attention core (per point, M = 16 neighbors) -----
__global__ __launch_bounds__(512, 2) void k_attn(
    const float* __restrict__ xyz, const float* __restrict__ feats,
    const int* __restrict__ idx_fps, const int* __restrict__ idx_knn,
    const float* __restrict__ Wv, const float* __restrict__ Wp1,
    const float* __restrict__ Wp2, const float* __restrict__ Wa2,
    float* __restrict__ out_xyz)
{
  __shared__ ushort lWv[COUT * CIN];     // 16 KB, 128B rows swz
  __shared__ ushort lWp1[COUT * 8];      // 2 KB, 16B rows linear
  __shared__ ushort lWp2[COUT * COUT];   // 32 KB, 256B rows swz
  __shared__ ushort lWka1[MID_ * CIN];   // 4 KB, 128B rows swz (holds -Wka1)
  __shared__ ushort lWpa1[MID_ * COUT];  // 8 KB, 256B rows swz
  __shared__ ushort sbuf[8 * 2560];      // per wave 5 KB: [0,4K) nfeat/t1, [4K,5K) a1

  const int tid = threadIdx.x;
  const int w = tid >> 6, l = tid & 63;
  const int r = l & 15, cq = l >> 4;

  for (int i = tid; i < COUT * CIN / 2; i += 512) {
    int row = i >> 5; int kp = (i & 31) * 2;
    int g = kp >> 3;
    *(uint*)((char*)lWv + row * 128 + ((g ^ (row & 7)) << 4) + (kp & 7) * 2)
        = pk2(Wv[row * CIN + kp], Wv[row * CIN + kp + 1]);
  }
  { // Wp1 padded: 128 rows x 4 pairs = 512
    int row = tid >> 2; int kp = (tid & 3) * 2;
    float lo = (kp < 3) ? Wp1[row * 3 + kp] : 0.f;
    float hi = (kp + 1 < 3) ? Wp1[row * 3 + kp + 1] : 0.f;
    *(uint*)((char*)lWp1 + row * 16 + kp * 2) = pk2(lo, hi);
  }
  for (int i = tid; i < COUT * CIN; i += 512) {
    int row = i >> 6; int kp = (i & 63) * 2;
    int g = kp >> 3;
    *(uint*)((char*)lWp2 + row * 256 + ((g ^ (row & 7)) << 4) + (kp & 7) * 2)
        = pk2(Wp2[row * COUT + kp], Wp2[row * COUT + kp + 1]);
  }
  for (int i = tid; i < MID_ * CIN / 2; i += 512) {   // -Wka1
    int row = i >> 5; int kp = (i & 31) * 2;
    int g = kp >> 3;
    const float* src = g_fw + 2048 + row * CIN + kp;
    *(uint*)((char*)lWka1 + row * 128 + ((g ^ (row & 7)) << 4) + (kp & 7) * 2)
        = pk2(-src[0], -src[1]);
  }
  for (int i = tid; i < MID_ * COUT / 2; i += 512) {  // Wpa1
    int row = i >> 6; int kp = (i & 63) * 2;
    int g = kp >> 3;
    const float* src = g_fw + 4096 + row * COUT + kp;
    *(uint*)((char*)lWpa1 + row * 256 + ((g ^ (row & 7)) << 4) + (kp & 7) * 2)
        = pk2(src[0], src[1]);
  }

  // register-resident B-frags: Wa2 (8 n-tiles), Wqa1 (2 tiles x 2 ks)
  s16x8 fWa2[8], fQ[2][2];
  #pragma unroll
  for (int t = 0; t < 8; ++t)
    fWa2[t] = ldfrag_g8(Wa2 + (16 * t + r) * MID_ + cq * 8);
  #pragma unroll
  for (int t = 0; t < 2; ++t)
    #pragma unroll
    for (int ks = 0; ks < 2; ++ks)
      fQ[t][ks] = ldfrag_g8(g_fw + (16 * t + r) * CIN + ks * 32 + cq * 8);

  __syncthreads();

  char* bufb = (char*)(sbuf + w * 2560);
  const int pid0 = (blockIdx.x * 8 + w) * 16;

  // ---- prologue: stage sfeat (row = point), qa1 GEMM for 16 points ----
  {
    const int p = pid0 + r;
    const int bb = p >> 13;
    const int si = idx_fps[p];
    const float* fs = feats + ((size_t)bb * N_ + si) * CIN;
    #pragma unroll
    for (int j = 0; j < 2; ++j) {
      int g = cq * 2 + j;
      int4 pks = pack8(*(const float4*)(fs + g * 8), *(const float4*)(fs + g * 8 + 4));
      *(int4*)(bufb + r * 128 + ((g ^ (r & 7)) << 4)) = pks;
      *(int4*)((char*)g_sfeat + (size_t)p * 128 + g * 16) = pks;
    }
    if (l < 48) {
      int pi = l / 3, j = l - pi * 3;
      int pp = pid0 + pi;
      out_xyz[(size_t)pp * 3 + j] =
          xyz[((size_t)(pp >> 13) * N_ + idx_fps[pp]) * 3 + j];
    }
  }
  f32x4 qa1[2];
  qa1[0] = (f32x4){0, 0, 0, 0}; qa1[1] = (f32x4){0, 0, 0, 0};
  {
    s16x8 fS[2];
    #pragma unroll
    for (int ks = 0; ks < 2; ++ks)
      fS[ks] = *(const s16x8*)(bufb + r * 128 + (((ks * 4 + cq) ^ (r & 7)) << 4));
    #pragma unroll
    for (int ks = 0; ks < 2; ++ks)
      #pragma unroll
      for (int t = 0; t < 2; ++t)
        qa1[t] = mfma16(fS[ks], fQ[t][ks], qa1[t]);
  }

  // ---- prefetch point 0 ----
  float4 pf0, pf1, pf2, pf3;
  float pxn0, pxn1, pxn2, pxs0, pxs1, pxs2;
  int nid_n;
  {
    int nid0 = idx_knn[(size_t)pid0 * K_ + r];
    const float* fn = feats + ((size_t)N_ * (pid0 >> 13) + nid0) * CIN + cq * 16;
    pf0 = ((const float4*)fn)[0]; pf1 = ((const float4*)fn)[1];
    pf2 = ((const float4*)fn)[2]; pf3 = ((const float4*)fn)[3];
    if (cq == 0) {
      const float* xn = xyz + ((size_t)N_ * (pid0 >> 13) + nid0) * 3;
      const float* xs = xyz + ((size_t)N_ * (pid0 >> 13) + idx_fps[pid0]) * 3;
      pxn0 = xn[0]; pxn1 = xn[1]; pxn2 = xn[2];
      pxs0 = xs[0]; pxs1 = xs[1]; pxs2 = xs[2];
    }
    nid_n = idx_knn[(size_t)(pid0 + 1) * K_ + r];
  }

  // ---- per-point loop ----
  #pragma unroll 1
  for (int i = 0; i < 16; ++i) {
    const int pid = pid0 + i;

    // stage A = n_feat (16 x 64 bf16, 128B swizzled rows) from prefetch regs
    {
      int g0 = cq * 2;
      *(int4*)(bufb + r * 128 + ((g0 ^ (r & 7)) << 4)) = pack8(pf0, pf1);
      *(int4*)(bufb + r * 128 + (((g0 + 1) ^ (r & 7)) << 4)) = pack8(pf2, pf3);
    }
    s16x8 fRel = {0, 0, 0, 0, 0, 0, 0, 0};
    if (cq == 0) {
      fRel[0] = (short)f2bf(pxn0 - pxs0);
      fRel[1] = (short)f2bf(pxn1 - pxs1);
      fRel[2] = (short)f2bf(pxn2 - pxs2);
    }

    // prefetch point i+1
    if (i < 15) {
      const int pidn = pid + 1;
      const int bn = pidn >> 13;
      const float* fn = feats + ((size_t)bn * N_ + nid_n) * CIN + cq * 16;
      float4 t0 = ((const float4*)fn)[0], t1 = ((const float4*)fn)[1];
      float4 t2 = ((const float4*)fn)[2], t3 = ((const float4*)fn)[3];
      if (cq == 0) {
        const float* xn = xyz + ((size_t)bn * N_ + nid_n) * 3;
        const float* xs = xyz + ((size_t)bn * N_ + idx_fps[pidn]) * 3;
        pxn0 = xn[0]; pxn1 = xn[1]; pxn2 = xn[2];
        pxs0 = xs[0]; pxs1 = xs[1]; pxs2 = xs[2];
      }
      if (i < 14) nid_n = idx_knn[(size_t)(pid + 2) * K_ + r];
      pf0 = t0; pf1 = t1; pf2 = t2; pf3 = t3;
    }

    // A-frags of staged nfeat
    s16x8 fA[2];
    #pragma unroll
    for (int ks = 0; ks < 2; ++ks)
      fA[ks] = *(const s16x8*)(bufb + r * 128 + (((ks * 4 + cq) ^ (r & 7)) << 4));

    // acc_v = nfeat @ Wv^T  (later += pe)
    f32x4 vv[8];
    #pragma unroll
    for (int t = 0; t < 8; ++t) vv[t] = (f32x4){0, 0, 0, 0};
    #pragma unroll
    for (int ks = 0; ks < 2; ++ks)
      #pragma unroll
      for (int t = 0; t < 8; ++t)
        vv[t] = mfma16(fA[ks], ldw128(lWv, 16 * t + r, ks * 4 + cq), vv[t]);

    // za1 = -(nfeat @ Wka1^T)   (2 mid-tiles)
    f32x4 za[2];
    za[0] = (f32x4){0, 0, 0, 0}; za[1] = (f32x4){0, 0, 0, 0};
    #pragma unroll
    for (int ks = 0; ks < 2; ++ks)
      #pragma unroll
      for (int t = 0; t < 2; ++t)
        za[t] = mfma16(fA[ks], ldw128(lWka1, 16 * t + r, ks * 4 + cq), za[t]);

    // t1 = relu(rel @ Wp1^T) -> buf
    #pragma unroll
    for (int t = 0; t < 8; ++t) {
      f32x4 z = {0, 0, 0, 0};
      f32x4 c = mfma16(fRel, *(const s16x8*)((const char*)lWp1 + (16 * t + r) * 16), z);
      st16(bufb, t, c, l, cq, true);
    }
    s16x8 fT[4];
    #pragma unroll
    for (int ks = 0; ks < 4; ++ks)
      fT[ks] = *(const s16x8*)(bufb + r * 256 + (((ks * 4 + cq) ^ (r & 7)) << 4));

    // acc_v += pe = t1 @ Wp2^T
    #pragma unroll
    for (int ks = 0; ks < 4; ++ks)
      #pragma unroll
      for (int t = 0; t < 8; ++t)
        vv[t] = mfma16(fT[ks], ldw256(lWp2, 16 * t + r, ks * 4 + cq), vv[t]);

    // za1 += t1 @ Wpa1^T
    #pragma unroll
    for (int ks = 0; ks < 4; ++ks)
      #pragma unroll
      for (int t = 0; t < 2; ++t)
        za[t] = mfma16(fT[ks], ldw256(lWpa1, 16 * t + r, ks * 4 + cq), za[t]);

    // za1 += qa1[point i] broadcast; relu; -> a1 buf
    const int ii = i & 3, iq = i >> 2;
    #pragma unroll
    for (int t = 0; t < 2; ++t) {
      float qsel = ii == 0 ? qa1[t][0] : ii == 1 ? qa1[t][1]
                 : ii == 2 ? qa1[t][2] : qa1[t][3];
      float qv = __shfl(qsel, (iq << 4) + (l & 15));
      #pragma unroll
      for (int rr = 0; rr < 4; ++rr) za[t][rr] += qv;
      st16_a1(bufb + 4096, t, za[t], l, cq);
    }
    // w = a1 @ Wa2^T
    s16x8 fA1 = *(const s16x8*)(bufb + 4096 + r * 64 + ((cq ^ (r & 3)) << 4));
    f32x4 ww[8];
    #pragma unroll
    for (int t = 0; t < 8; ++t) {
      f32x4 z = {0, 0, 0, 0};
      ww[t] = mfma16(fA1, fWa2[t], z);
    }
    // softmax over neighbors (rows) + weighted sum of vpe (= acc_v)
    #pragma unroll
    for (int t = 0; t < 8; ++t) {
      float m = fmaxf(fmaxf(ww[t][0], ww[t][1]), fmaxf(ww[t][2], ww[t][3]));
      m = fmaxf(m, __shfl_xor(m, 16));
      m = fmaxf(m, __shfl_xor(m, 32));
      float e0 = __expf(ww[t][0] - m), e1 = __expf(ww[t][1] - m);
      float e2 = __expf(ww[t][2] - m), e3 = __expf(ww[t][3] - m);
      float ss = e0 + e1 + e2 + e3;
      ss += __shfl_xor(ss, 16);
      ss += __shfl_xor(ss, 32);
      float acc = e0 * vv[t][0] + e1 * vv[t][1] + e2 * vv[t][2] + e3 * vv[t][3];
      acc += __shfl_xor(acc, 16);
      acc += __shfl_xor(acc, 32);
      float outv = acc / ss;
      if (cq == (t >> 2)) {
        int colp = (l & 15) + 16 * t;
        *(ushort*)((char*)g_attn + (size_t)pid * 256 + colp * 2) = f2bf(outv);
      }
    }
  }
}

// ---------------- Kernel 2: proj + res + LN + post (M = 16 points) ----------
__global__ __launch_bounds__(512, 2) void k_post(
    const float* __restrict__ Wproj, const float* __restrict__ Wres,
    const float* __restrict__ Wpost, const float* __restrict__ ln_w,
    const float* __restrict__ ln_b, float* __restrict__ out_main)
{
  __shared__ ushort lWpj[COUT * COUT];
  __shared__ ushort lWrs[COUT * CIN];
  __shared__ ushort lWps[COUT * COUT];
  __shared__ float  llnw[COUT], llnb[COUT];
  __shared__ ushort sbuf[8 * 16 * COUT];

  const int tid = threadIdx.x;
  const int w = tid >> 6, l = tid & 63;
  const int r = l & 15, cq = l >> 4;

  for (int i = tid; i < COUT * CIN; i += 512) {
    int row = i >> 6; int kp = (i & 63) * 2;
    int g = kp >> 3;
    *(uint*)((char*)lWpj + row * 256 + ((g ^ (row & 7)) << 4) + (kp & 7) * 2)
        = pk2(Wproj[row * COUT + kp], Wproj[row * COUT + kp + 1]);
  }
  for (int i = tid; i < COUT * CIN / 2; i += 512) {
    int row = i >> 5; int kp = (i & 31) * 2;
    int g = kp >> 3;
    *(uint*)((char*)lWrs + row * 128 + ((g ^ (row & 7)) << 4) + (kp & 7) * 2)
        = pk2(Wres[row * CIN + kp], Wres[row * CIN + kp + 1]);
  }
  for (int i = tid; i < COUT * CIN; i += 512) {
    int row = i >> 6; int kp = (i & 63) * 2;
    int g = kp >> 3;
    *(uint*)((char*)lWps + row * 256 + ((g ^ (row & 7)) << 4) + (kp & 7) * 2)
        = pk2(Wpost[row * COUT + kp], Wpost[row * COUT + kp + 1]);
  }
  if (tid < COUT) { llnw[tid] = ln_w[tid]; llnb[tid] = ln_b[tid]; }
  __syncthreads();

  const int T = blockIdx.x * 8 + w;     // 16-point tile id
  char* bufb = (char*)(sbuf + w * 16 * COUT);

  f32x4 acc[8];
  #pragma unroll
  for (int t = 0; t < 8; ++t) acc[t] = (f32x4){0, 0, 0, 0};

  s16x8 fA[4];
  #pragma unroll
  for (int ks = 0; ks < 4; ++ks)
    fA[ks] = *(const s16x8*)(g_attn + ((size_t)T * 16 + r) * COUT + ks * 32 + cq * 8);
  #pragma unroll
  for (int ks = 0; ks < 4; ++ks)
    #pragma unroll
    for (int t = 0; t < 8; ++t)
      acc[t] = mfma16(fA[ks], ldw256(lWpj, 16 * t + r, ks * 4 + cq), acc[t]);

  s16x8 fS[2];
  #pragma unroll
  for (int ks = 0; ks < 2; ++ks)
    fS[ks] = *(const s16x8*)(g_sfeat + ((size_t)T * 16 + r) * CIN + ks * 32 + cq * 8);
  #pragma unroll
  for (int ks = 0; ks < 2; ++ks)
    #pragma unroll
    for (int t = 0; t < 8; ++t)
      acc[t] = mfma16(fS[ks], ldw128(lWrs, 16 * t + r, ks * 4 + cq), acc[t]);

  // LayerNorm per row (= point)
  #pragma unroll
  for (int rr = 0; rr < 4; ++rr) {
    float s1 = 0.f, s2 = 0.f;
    #pragma unroll
    for (int t = 0; t < 8; ++t) { float v = acc[t][rr]; s1 += v; s2 += v * v; }
    #pragma unroll
    for (int off = 1; off < 16; off <<= 1) {
      s1 += __shfl_xor(s1, off);
      s2 += __shfl_xor(s2, off);
    }
    float mu = s1 * (1.f / COUT);
    float rs = rsqrtf(s2 * (1.f / COUT) - mu * mu + EPS_);
    #pragma unroll
    for (int t = 0; t < 8; ++t) {
      int col = (l & 15) + 16 * t;
      acc[t][rr] = (acc[t][rr] - mu) * rs * llnw[col] + llnb[col];
    }
  }
  #pragma unroll
  for (int t = 0; t < 8; ++t) st16(bufb, t, acc[t], l, cq, false);

  // post conv GEMM
  s16x8 fZ[4];
  #pragma unroll
  for (int ks = 0; ks < 4; ++ks)
    fZ[ks] = *(const s16x8*)(bufb + r * 256 + (((ks * 4 + cq) ^ (r & 7)) << 4));
  f32x4 po[8];
  #pragma unroll
  for (int t = 0; t < 8; ++t) po[t] = (f32x4){0, 0, 0, 0};
  #pragma unroll
  for (int ks = 0; ks < 4; ++ks)
    #pragma unroll
    for (int t = 0; t < 8; ++t)
      po[t] = mfma16(fZ[ks], ldw256(lWps, 16 * t + r, ks * 4 + cq), po[t]);

  // write pre-GN post + per-tile GN partials (group = tile t)
  #pragma unroll
  for (int t = 0; t < 8; ++t) {
    float s1 = po[t][0] + po[t][1] + po[t][2] + po[t][3];
    float s2 = po[t][0] * po[t][0] + po[t][1] * po[t][1]
             + po[t][2] * po[t][2] + po[t][3] * po[t][3];
    #pragma unroll
    for (int off = 1; off < 64; off <<= 1) {
      s1 += __shfl_xor(s1, off);
      s2 += __shfl_xor(s2, off);
    }
    if (l == 0) {
      g_part[((size_t)T * 8 + t) * 2] = s1;
      g_part[((size_t)T * 8 + t) * 2 + 1] = s2;
    }
    #pragma unroll
    for (int rr = 0; rr < 4; ++rr) {
      int row = T * 16 + cq * 4 + rr;
      out_main[(size_t)row * COUT + (l & 15) + 16 * t] = po[t][rr];
    }
  }
}

// ---------------- GroupNorm finish + apply ----------------------------------
__global__ void k_gn_finish(void) {
  int bg = blockIdx.x;          // 0..31  (b*8+g)
  int b = bg >> 3, g = bg & 7;
  int t = threadIdx.x;          // 64
  float s1 = 0.f, s2 = 0.f;
  for (int i = t; i < 512; i += 64) {
    size_t T = (size_t)b * 512 + i;
    s1 += g_part[(T * 8 + g) * 2];
    s2 += g_part[(T * 8 + g) * 2 + 1];
  }
  #pragma unroll
  for (int off = 1; off < 64; off <<= 1) {
    s1 += __shfl_xor(s1, off);
    s2 += __shfl_xor(s2, off);
  }
  if (t == 0) {
    float n = (float)S_ * 16.f;
    float mu = s1 / n;
    float var = s2 / n - mu * mu;
    g_stats[bg * 2] = mu;
    g_stats[bg * 2 + 1] = rsqrtf(var + EPS_);
  }
}

__global__ __launch_bounds__(256) void k_gn_apply(
    float* __restrict__ x, const float* __restrict__ gn_w,
    const float* __restrict__ gn_b)
{
  const int i = blockIdx.x * 256 + threadIdx.x;   // float4 index
  if (i >= B_ * S_ * (COUT / 4)) return;
  const int c = (i & 31) * 4;
  const int g = c >> 4;
  const int b = i >> 18;
  const float m = g_stats[(b * 8 + g) * 2];
  const float rv = g_stats[(b * 8 + g) * 2 + 1];
  float4 v = ((float4*)x)[i];
  v.x = fmaxf((v.x - m) * rv * gn_w[c + 0] + gn_b[c + 0], 0.f);
  v.y = fmaxf((v.y - m) * rv * gn_w[c + 1] + gn_b[c + 1], 0.f);
  v.z = fmaxf((v.z - m) * rv * gn_w[c + 2] + gn_b[c + 2], 0.f);
  v.w = fmaxf((v.w - m) * rv * gn_w[c + 3] + gn_b[c + 3], 0.f);
  ((float4*)x)[i] = v;
}

extern "C" void kernel_launch(void* const* d_in, const int* in_sizes, int n_in,
                              void* d_out, int out_size, void* d_ws, size_t ws_size,
                              hipStream_t stream) {
  const float* xyz     = (const float*)d_in[0];
  const float* feats   = (const float*)d_in[1];
  const int*   idx_fps = (const int*)d_in[2];
  const int*   idx_knn = (const int*)d_in[3];
  const float* Wq    = (const float*)d_in[4];
  const float* Wk    = (const float*)d_in[5];
  const float* Wv    = (const float*)d_in[6];
  const float* Wp1   = (const float*)d_in[7];
  const float* Wp2   = (const float*)d_in[8];
  const float* Wa1   = (const float*)d_in[9];
  const float* Wa2   = (const float*)d_in[10];
  const float* Wproj = (const float*)d_in[11];
  const float* ln_w  = (const float*)d_in[12];
  const float* ln_b  = (const float*)d_in[13];
  const float* Wres  = (const float*)d_in[14];
  const float* Wpost = (const float*)d_in[15];
  const float* gn_w  = (const float*)d_in[16];
  const float* gn_b  = (const float*)d_in[17];

  float* out      = (float*)d_out;
  float* out_xyz  = out;
  float* out_main = out + (size_t)B_ * S_ * 3;

  k_fuse<<<dim3(32), dim3(256), 0, stream>>>(Wq, Wk, Wp2, Wa1);
  k_attn<<<dim3(256), dim3(512), 0, stream>>>(
      xyz, feats, idx_fps, idx_knn, Wv, Wp1, Wp2, Wa2, out_xyz);
  k_post<<<dim3(256), dim3(512), 0, stream>>>(
      Wproj, Wres, Wpost, ln_w, ln_b, out_main);
  k_gn_finish<<<dim3(32), dim3(64), 0, stream>>>();
  k_gn_apply<<<dim3((B_ * S_ * (COUT / 4) + 255) / 256), dim3(256), 0, stream>>>(
      out_main, gn_w, gn_b);
}